// Round 5
// baseline (506.765 us; speedup 1.0000x reference)
//
#include <hip/hip_runtime.h>
#include <hip/hip_bf16.h>

#define N_NODES 20000
#define N_EDGES 320000
#define M_PAD   20096   // 157 * 128

typedef __attribute__((ext_vector_type(8))) short short8;
typedef __attribute__((ext_vector_type(4))) float f32x4;

__device__ __forceinline__ float b2f(short s){
  union { unsigned u; float f; } c;
  c.u = ((unsigned)(unsigned short)s) << 16;
  return c.f;
}
__device__ __forceinline__ short f2b(float f){
  union { float f; unsigned u; } c;
  c.f = f;
  unsigned r = (c.u + 0x7fffu + ((c.u >> 16) & 1u)) >> 16;
  return (short)r;
}

// ---------------- utility ----------------
__global__ void k_zero_i(int* p, int n){
  int i = blockIdx.x * 256 + threadIdx.x;
  if (i < n) p[i] = 0;
}

// ---------------- CSR build ----------------
__global__ void k_deg(const int* row, int* deg){
  int e = blockIdx.x * 256 + threadIdx.x;
  if (e < N_EDGES) atomicAdd(&deg[row[e]], 1);
}

__global__ void k_scan(const int* deg, int* offs, float* dinv){
  __shared__ int part[256];
  int t = threadIdx.x;
  int base = t * 79;                 // 256*79 = 20224 >= 20000
  int s = 0;
  for (int k = 0; k < 79; k++){
    int i = base + k;
    if (i < N_NODES) s += deg[i];
  }
  part[t] = s;
  __syncthreads();
  for (int off = 1; off < 256; off <<= 1){
    int v2 = 0;
    if (t >= off) v2 = part[t - off];
    __syncthreads();
    if (t >= off) part[t] += v2;
    __syncthreads();
  }
  int run = (t > 0) ? part[t - 1] : 0;
  for (int k = 0; k < 79; k++){
    int i = base + k;
    if (i < N_NODES){
      offs[i] = run;
      int d = deg[i];
      run += d;
      dinv[i] = (d > 0) ? rsqrtf((float)d) : 0.0f;
    }
  }
  if (t == 255) offs[N_NODES] = part[255];
}

__global__ void k_fill(const int* row, const int* col, const int* offs,
                       int* cursor, const float* dinv, int* ccol, float* cw){
  int e = blockIdx.x * 256 + threadIdx.x;
  if (e >= N_EDGES) return;
  int r = row[e];
  int c = col[e];
  int pos = offs[r] + atomicAdd(&cursor[r], 1);
  ccol[pos] = c;
  cw[pos] = -dinv[r] * dinv[c];
}

// ---------------- staging: f32 x -> bf16 padded Xb [M_PAD][Kp] ----------------
__global__ void k_xb(const float* x, short* Xb, int cin, int Kp){
  int i = blockIdx.x;
  int c = threadIdx.x;
  if (c >= Kp) return;
  short out = 0;
  if (i < N_NODES && c < cin)
    out = f2b(x[(long long)i * cin + c]);
  Xb[(long long)i * Kp + c] = out;
}

// Z1b[i][c] = bf16( sum_j cw[j] * Xb[ccol[j]][c] )   (pad rows/cols -> 0)
__global__ void k_lhat1(const short* Xb, const int* offs, const int* ccol,
                        const float* cw, short* Z1b, int Kp){
  int i = blockIdx.x;
  int c = threadIdx.x;
  if (c >= Kp) return;
  short out = 0;
  if (i < N_NODES){
    int s = offs[i];
    int e = offs[i + 1];
    float acc = 0.0f;
    for (int j = s; j < e; j++)
      acc += cw[j] * b2f(Xb[(long long)ccol[j] * Kp + c]);
    out = f2b(acc);
  }
  Z1b[(long long)i * Kp + c] = out;
}

// Z2b[i][c] = bf16( 2 * sum_j cw[j] * Z1b[ccol[j]][c] - x[i][c] )
__global__ void k_lhat2(const float* x, const short* Z1b, const int* offs,
                        const int* ccol, const float* cw, short* Z2b,
                        int cin, int Kp){
  int i = blockIdx.x;
  int c = threadIdx.x;
  if (c >= Kp) return;
  short out = 0;
  if (i < N_NODES){
    int s = offs[i];
    int e = offs[i + 1];
    float acc = 0.0f;
    for (int j = s; j < e; j++)
      acc += cw[j] * b2f(Z1b[(long long)ccol[j] * Kp + c]);
    float xv = (c < cin) ? x[(long long)i * cin + c] : 0.0f;
    out = f2b(2.0f * acc - xv);
  }
  Z2b[(long long)i * Kp + c] = out;
}

// WT[n][g*Kp + kk] = bf16(W_g[kk][n]) for kk<cin else 0    (cout x 3Kp, K-contig)
__global__ void k_wt(const float* W0, const float* W1, const float* W2,
                     short* WT, int cin, int cout, int Kp){
  int Kpad = 3 * Kp;
  int idx = blockIdx.x * 256 + threadIdx.x;
  if (idx >= cout * Kpad) return;
  int n = idx / Kpad;
  int k = idx % Kpad;
  int g = k / Kp;
  int kk = k % Kp;
  short v = 0;
  if (kk < cin){
    const float* W = (g == 0) ? W0 : ((g == 1) ? W1 : W2);
    v = f2b(W[(long long)kk * cout + n]);
  }
  WT[idx] = v;
}

// ---------------- MFMA GEMM: C = relu(A0@W0 + A1@W1 + A2@W2 + bias), f32 out ----
__global__ __launch_bounds__(256)
void k_gemm(const short* A0, const short* A1, const short* A2,
            const short* BT,   // cout x 3Kp bf16 (row-major, K-contig)
            const float* bias, float* C, int Kp, int cout){
  __shared__ short aLds[128 * 40];
  __shared__ short bLds[128 * 40];
  int tid = threadIdx.x;
  int lane = tid & 63;
  int wave = tid >> 6;
  int wm = wave >> 1;
  int wn = wave & 1;
  int bm0 = blockIdx.x * 128;
  int bn0 = blockIdx.y * 128;
  int Kpad3 = 3 * Kp;

  f32x4 acc[4][4];
  for (int m = 0; m < 4; m++)
    for (int n = 0; n < 4; n++)
      acc[m][n] = (f32x4){0.0f, 0.0f, 0.0f, 0.0f};

  for (int g = 0; g < 3; g++){
    const short* Ag = (g == 0) ? A0 : ((g == 1) ? A1 : A2);
    for (int kt = 0; kt < Kp; kt += 32){
      #pragma unroll
      for (int i = 0; i < 2; i++){
        int chunk = tid + i * 256;       // 0..511
        int r = chunk >> 2;              // 0..127
        int kc = (chunk & 3) * 8;        // 0,8,16,24
        short8 av = *(const short8*)&Ag[(long long)(bm0 + r) * Kp + kt + kc];
        *(short8*)&aLds[r * 40 + kc] = av;
        short8 bv = *(const short8*)&BT[(long long)(bn0 + r) * Kpad3 + g * Kp + kt + kc];
        *(short8*)&bLds[r * 40 + kc] = bv;
      }
      __syncthreads();
      short8 af[4];
      short8 bfr[4];
      #pragma unroll
      for (int m = 0; m < 4; m++)
        af[m] = *(const short8*)&aLds[(wm * 64 + m * 16 + (lane & 15)) * 40 + (lane >> 4) * 8];
      #pragma unroll
      for (int n = 0; n < 4; n++)
        bfr[n] = *(const short8*)&bLds[(wn * 64 + n * 16 + (lane & 15)) * 40 + (lane >> 4) * 8];
      #pragma unroll
      for (int m = 0; m < 4; m++)
        #pragma unroll
        for (int n = 0; n < 4; n++)
          acc[m][n] = __builtin_amdgcn_mfma_f32_16x16x32_bf16(af[m], bfr[n], acc[m][n], 0, 0, 0);
      __syncthreads();
    }
  }

  for (int m = 0; m < 4; m++){
    for (int n = 0; n < 4; n++){
      int gc = bn0 + wn * 64 + n * 16 + (lane & 15);
      float bv = bias[gc];
      for (int r = 0; r < 4; r++){
        int gr = bm0 + wm * 64 + m * 16 + (lane >> 4) * 4 + r;
        if (gr < N_NODES){
          float v2 = acc[m][n][r] + bv;
          if (v2 < 0.0f) v2 = 0.0f;
          C[(long long)gr * cout + gc] = v2;
        }
      }
    }
  }
}

extern "C" void kernel_launch(void* const* d_in, const int* in_sizes, int n_in,
                              void* d_out, int out_size, void* d_ws, size_t ws_size,
                              hipStream_t stream){
  const float* v = (const float*)d_in[0];
  const int* edges = (const int*)d_in[1];
  const int* row = edges;
  const int* col = edges + N_EDGES;

  const float* W00 = (const float*)d_in[2];
  const float* W01 = (const float*)d_in[3];
  const float* W02 = (const float*)d_in[4];
  const float* b0  = (const float*)d_in[5];
  const float* W10 = (const float*)d_in[6];
  const float* W11 = (const float*)d_in[7];
  const float* W12 = (const float*)d_in[8];
  const float* b1  = (const float*)d_in[9];
  const float* W20 = (const float*)d_in[10];
  const float* W21 = (const float*)d_in[11];
  const float* W22 = (const float*)d_in[12];
  const float* b2  = (const float*)d_in[13];

  // workspace layout (plain offsets, ~35 MB)
  int* ibase = (int*)d_ws;
  int* deg = ibase;                         // 20000
  int* cursor = ibase + 20000;              // 20000 (adjacent to deg for k_zero_i)
  int* offs = ibase + 40000;                // 20001
  float* dinv = (float*)(ibase + 60002);    // 20000
  int* ccol = ibase + 80002;                // 320000
  float* cw = (float*)(ibase + 400002);     // 320000
  short* Xb  = (short*)(ibase + 720002);                  // M_PAD*256 bf16
  short* Z1b = Xb + (long long)M_PAD * 256;
  short* Z2b = Z1b + (long long)M_PAD * 256;
  short* WT  = Z2b + (long long)M_PAD * 256;              // 512*768 bf16

  float* out = (float*)d_out;
  float* x1 = out;
  float* x2 = out + (long long)N_NODES * 128;
  float* x3 = out + (long long)N_NODES * (128 + 256);

  k_zero_i<<<(40000 + 255) / 256, 256, 0, stream>>>(deg, 40000);
  k_deg<<<(N_EDGES + 255) / 256, 256, 0, stream>>>(row, deg);
  k_scan<<<1, 256, 0, stream>>>(deg, offs, dinv);
  k_fill<<<(N_EDGES + 255) / 256, 256, 0, stream>>>(row, col, offs, cursor, dinv, ccol, cw);

  // ---- layer 0: cin=86, Kp=96, cout=128 ----
  k_xb<<<M_PAD, 96, 0, stream>>>(v, Xb, 86, 96);
  k_lhat1<<<M_PAD, 96, 0, stream>>>(Xb, offs, ccol, cw, Z1b, 96);
  k_lhat2<<<M_PAD, 96, 0, stream>>>(v, Z1b, offs, ccol, cw, Z2b, 86, 96);
  k_wt<<<(128 * 288 + 255) / 256, 256, 0, stream>>>(W00, W01, W02, WT, 86, 128, 96);
  {
    dim3 g(M_PAD / 128, 128 / 128);
    k_gemm<<<g, 256, 0, stream>>>(Xb, Z1b, Z2b, WT, b0, x1, 96, 128);
  }

  // ---- layer 1: cin=128, Kp=128, cout=256 ----
  k_xb<<<M_PAD, 128, 0, stream>>>(x1, Xb, 128, 128);
  k_lhat1<<<M_PAD, 128, 0, stream>>>(Xb, offs, ccol, cw, Z1b, 128);
  k_lhat2<<<M_PAD, 128, 0, stream>>>(x1, Z1b, offs, ccol, cw, Z2b, 128, 128);
  k_wt<<<(256 * 384 + 255) / 256, 256, 0, stream>>>(W10, W11, W12, WT, 128, 256, 128);
  {
    dim3 g(M_PAD / 128, 256 / 128);
    k_gemm<<<g, 256, 0, stream>>>(Xb, Z1b, Z2b, WT, b1, x2, 128, 256);
  }

  // ---- layer 2: cin=256, Kp=256, cout=512 ----
  k_xb<<<M_PAD, 256, 0, stream>>>(x2, Xb, 256, 256);
  k_lhat1<<<M_PAD, 256, 0, stream>>>(Xb, offs, ccol, cw, Z1b, 256);
  k_lhat2<<<M_PAD, 256, 0, stream>>>(x2, Z1b, offs, ccol, cw, Z2b, 256, 256);
  k_wt<<<(512 * 768 + 255) / 256, 256, 0, stream>>>(W20, W21, W22, WT, 256, 512, 256);
  {
    dim3 g(M_PAD / 128, 512 / 128);
    k_gemm<<<g, 256, 0, stream>>>(Xb, Z1b, Z2b, WT, b2, x3, 256, 512);
  }
}

// Round 6
// 336.587 us; speedup vs baseline: 1.5056x; 1.5056x over previous
//
#include <hip/hip_runtime.h>
#include <hip/hip_bf16.h>

#define N_NODES 20000
#define N_EDGES 320000
#define M_PAD   20096   // 157 * 128

typedef __attribute__((ext_vector_type(8))) short short8;
typedef __attribute__((ext_vector_type(4))) short bfx4;
typedef __attribute__((ext_vector_type(4))) float f32x4;

__device__ __forceinline__ float b2f(short s){
  union { unsigned u; float f; } c;
  c.u = ((unsigned)(unsigned short)s) << 16;
  return c.f;
}
__device__ __forceinline__ short f2b(float f){
  union { float f; unsigned u; } c;
  c.f = f;
  unsigned r = (c.u + 0x7fffu + ((c.u >> 16) & 1u)) >> 16;
  return (short)r;
}

// ---------------- utility ----------------
__global__ void k_zero_i(int* p, int n){
  int i = blockIdx.x * 256 + threadIdx.x;
  if (i < n) p[i] = 0;
}

// ---------------- CSR build ----------------
__global__ void k_deg(const int* row, int* deg){
  int e = blockIdx.x * 256 + threadIdx.x;
  if (e < N_EDGES) atomicAdd(&deg[row[e]], 1);
}

__global__ void k_scan(const int* deg, int* offs, float* dinv){
  __shared__ int part[256];
  int t = threadIdx.x;
  int base = t * 79;                 // 256*79 = 20224 >= 20000
  int s = 0;
  for (int k = 0; k < 79; k++){
    int i = base + k;
    if (i < N_NODES) s += deg[i];
  }
  part[t] = s;
  __syncthreads();
  for (int off = 1; off < 256; off <<= 1){
    int v2 = 0;
    if (t >= off) v2 = part[t - off];
    __syncthreads();
    if (t >= off) part[t] += v2;
    __syncthreads();
  }
  int run = (t > 0) ? part[t - 1] : 0;
  for (int k = 0; k < 79; k++){
    int i = base + k;
    if (i < N_NODES){
      offs[i] = run;
      int d = deg[i];
      run += d;
      dinv[i] = (d > 0) ? rsqrtf((float)d) : 0.0f;
    }
  }
  if (t == 255) offs[N_NODES] = part[255];
}

__global__ void k_fill(const int* row, const int* col, const int* offs,
                       int* cursor, const float* dinv, int* ccol, float* cw){
  int e = blockIdx.x * 256 + threadIdx.x;
  if (e >= N_EDGES) return;
  int r = row[e];
  int c = col[e];
  int pos = offs[r] + atomicAdd(&cursor[r], 1);
  ccol[pos] = c;
  cw[pos] = -dinv[r] * dinv[c];
}

// ---------------- staging: f32 x -> bf16 padded Xb [M_PAD][lda], 4 cols/lane ----
__global__ __launch_bounds__(256)
void k_xbv(const float* x, short* Xb, int cin, int lgLpn, int lda){
  long long gl = (long long)blockIdx.x * 256 + threadIdx.x;
  int node = (int)(gl >> lgLpn);
  if (node >= M_PAD) return;
  int c0 = (int)(gl & ((1 << lgLpn) - 1)) * 4;
  bfx4 o;
  if (node < N_NODES && (cin & 3) == 0 && c0 + 4 <= cin){
    f32x4 xv = *(const f32x4*)&x[(long long)node * cin + c0];
    o[0] = f2b(xv[0]); o[1] = f2b(xv[1]); o[2] = f2b(xv[2]); o[3] = f2b(xv[3]);
  } else {
    for (int t = 0; t < 4; t++){
      int c = c0 + t;
      float val = (node < N_NODES && c < cin) ? x[(long long)node * cin + c] : 0.0f;
      o[t] = f2b(val);
    }
  }
  *(bfx4*)&Xb[(long long)node * lda + c0] = o;
}

// Z1[node][c0..c0+3] = bf16( sum_j cw[j] * X[ccol[j]][c0..c0+3] ); 4-edge unroll
__global__ __launch_bounds__(256)
void k_lhat1v(const short* X, const int* offs, const int* ccol, const float* cw,
              short* Z1, int lgLpn, int lda){
  long long gl = (long long)blockIdx.x * 256 + threadIdx.x;
  int node = (int)(gl >> lgLpn);
  if (node >= N_NODES) return;
  int c0 = (int)(gl & ((1 << lgLpn) - 1)) * 4;
  int s = offs[node];
  int e = offs[node + 1];
  float a0 = 0.0f, a1 = 0.0f, a2 = 0.0f, a3 = 0.0f;
  int j = s;
  for (; j + 4 <= e; j += 4){
    int i0 = ccol[j];     int i1 = ccol[j + 1];
    int i2 = ccol[j + 2]; int i3 = ccol[j + 3];
    float w0 = cw[j];     float w1 = cw[j + 1];
    float w2 = cw[j + 2]; float w3 = cw[j + 3];
    bfx4 v0 = *(const bfx4*)&X[(long long)i0 * lda + c0];
    bfx4 v1 = *(const bfx4*)&X[(long long)i1 * lda + c0];
    bfx4 v2 = *(const bfx4*)&X[(long long)i2 * lda + c0];
    bfx4 v3 = *(const bfx4*)&X[(long long)i3 * lda + c0];
    a0 += w0 * b2f(v0[0]) + w1 * b2f(v1[0]) + w2 * b2f(v2[0]) + w3 * b2f(v3[0]);
    a1 += w0 * b2f(v0[1]) + w1 * b2f(v1[1]) + w2 * b2f(v2[1]) + w3 * b2f(v3[1]);
    a2 += w0 * b2f(v0[2]) + w1 * b2f(v1[2]) + w2 * b2f(v2[2]) + w3 * b2f(v3[2]);
    a3 += w0 * b2f(v0[3]) + w1 * b2f(v1[3]) + w2 * b2f(v2[3]) + w3 * b2f(v3[3]);
  }
  for (; j < e; j++){
    int i0 = ccol[j];
    float w0 = cw[j];
    bfx4 v0 = *(const bfx4*)&X[(long long)i0 * lda + c0];
    a0 += w0 * b2f(v0[0]);
    a1 += w0 * b2f(v0[1]);
    a2 += w0 * b2f(v0[2]);
    a3 += w0 * b2f(v0[3]);
  }
  bfx4 o;
  o[0] = f2b(a0); o[1] = f2b(a1); o[2] = f2b(a2); o[3] = f2b(a3);
  *(bfx4*)&Z1[(long long)node * lda + c0] = o;
}

// Z2[node][c] = bf16( 2 * sum_j cw[j] * Z1[ccol[j]][c] - x[node][c] )
__global__ __launch_bounds__(256)
void k_lhat2v(const float* x, const short* Z1, const int* offs, const int* ccol,
              const float* cw, short* Z2, int cin, int lgLpn, int lda){
  long long gl = (long long)blockIdx.x * 256 + threadIdx.x;
  int node = (int)(gl >> lgLpn);
  if (node >= N_NODES) return;
  int c0 = (int)(gl & ((1 << lgLpn) - 1)) * 4;
  int s = offs[node];
  int e = offs[node + 1];
  float a0 = 0.0f, a1 = 0.0f, a2 = 0.0f, a3 = 0.0f;
  int j = s;
  for (; j + 4 <= e; j += 4){
    int i0 = ccol[j];     int i1 = ccol[j + 1];
    int i2 = ccol[j + 2]; int i3 = ccol[j + 3];
    float w0 = cw[j];     float w1 = cw[j + 1];
    float w2 = cw[j + 2]; float w3 = cw[j + 3];
    bfx4 v0 = *(const bfx4*)&Z1[(long long)i0 * lda + c0];
    bfx4 v1 = *(const bfx4*)&Z1[(long long)i1 * lda + c0];
    bfx4 v2 = *(const bfx4*)&Z1[(long long)i2 * lda + c0];
    bfx4 v3 = *(const bfx4*)&Z1[(long long)i3 * lda + c0];
    a0 += w0 * b2f(v0[0]) + w1 * b2f(v1[0]) + w2 * b2f(v2[0]) + w3 * b2f(v3[0]);
    a1 += w0 * b2f(v0[1]) + w1 * b2f(v1[1]) + w2 * b2f(v2[1]) + w3 * b2f(v3[1]);
    a2 += w0 * b2f(v0[2]) + w1 * b2f(v1[2]) + w2 * b2f(v2[2]) + w3 * b2f(v3[2]);
    a3 += w0 * b2f(v0[3]) + w1 * b2f(v1[3]) + w2 * b2f(v2[3]) + w3 * b2f(v3[3]);
  }
  for (; j < e; j++){
    int i0 = ccol[j];
    float w0 = cw[j];
    bfx4 v0 = *(const bfx4*)&Z1[(long long)i0 * lda + c0];
    a0 += w0 * b2f(v0[0]);
    a1 += w0 * b2f(v0[1]);
    a2 += w0 * b2f(v0[2]);
    a3 += w0 * b2f(v0[3]);
  }
  float xv0 = 0.0f, xv1 = 0.0f, xv2 = 0.0f, xv3 = 0.0f;
  if ((cin & 3) == 0 && c0 + 4 <= cin){
    f32x4 xv = *(const f32x4*)&x[(long long)node * cin + c0];
    xv0 = xv[0]; xv1 = xv[1]; xv2 = xv[2]; xv3 = xv[3];
  } else {
    if (c0 + 0 < cin) xv0 = x[(long long)node * cin + c0 + 0];
    if (c0 + 1 < cin) xv1 = x[(long long)node * cin + c0 + 1];
    if (c0 + 2 < cin) xv2 = x[(long long)node * cin + c0 + 2];
    if (c0 + 3 < cin) xv3 = x[(long long)node * cin + c0 + 3];
  }
  bfx4 o;
  o[0] = f2b(2.0f * a0 - xv0);
  o[1] = f2b(2.0f * a1 - xv1);
  o[2] = f2b(2.0f * a2 - xv2);
  o[3] = f2b(2.0f * a3 - xv3);
  *(bfx4*)&Z2[(long long)node * lda + c0] = o;
}

// WT[n][g*Kp + kk] = bf16(W_g[kk][n]) for kk<cin else 0    (cout x 3Kp, K-contig)
__global__ void k_wt(const float* W0, const float* W1, const float* W2,
                     short* WT, int cin, int cout, int Kp){
  int Kpad = 3 * Kp;
  int idx = blockIdx.x * 256 + threadIdx.x;
  if (idx >= cout * Kpad) return;
  int n = idx / Kpad;
  int k = idx % Kpad;
  int g = k / Kp;
  int kk = k % Kp;
  short v = 0;
  if (kk < cin){
    const float* W = (g == 0) ? W0 : ((g == 1) ? W1 : W2);
    v = f2b(W[(long long)kk * cout + n]);
  }
  WT[idx] = v;
}

// ---------------- MFMA GEMM: C = relu(A0@W0 + A1@W1 + A2@W2 + bias), f32 out ----
__global__ __launch_bounds__(256)
void k_gemm(const short* A0, const short* A1, const short* A2,
            const short* BT,   // cout x 3Kext bf16 (row-major, K-contig)
            const float* bias, float* C, int lda, int Kext, int cout){
  __shared__ short aLds[128 * 40];
  __shared__ short bLds[128 * 40];
  int tid = threadIdx.x;
  int lane = tid & 63;
  int wave = tid >> 6;
  int wm = wave >> 1;
  int wn = wave & 1;
  int bm0 = blockIdx.x * 128;
  int bn0 = blockIdx.y * 128;
  int Kpad3 = 3 * Kext;

  f32x4 acc[4][4];
  for (int m = 0; m < 4; m++)
    for (int n = 0; n < 4; n++)
      acc[m][n] = (f32x4){0.0f, 0.0f, 0.0f, 0.0f};

  for (int g = 0; g < 3; g++){
    const short* Ag = (g == 0) ? A0 : ((g == 1) ? A1 : A2);
    for (int kt = 0; kt < Kext; kt += 32){
      #pragma unroll
      for (int i = 0; i < 2; i++){
        int chunk = tid + i * 256;       // 0..511
        int r = chunk >> 2;              // 0..127
        int kc = (chunk & 3) * 8;        // 0,8,16,24
        short8 av = *(const short8*)&Ag[(long long)(bm0 + r) * lda + kt + kc];
        *(short8*)&aLds[r * 40 + kc] = av;
        short8 bv = *(const short8*)&BT[(long long)(bn0 + r) * Kpad3 + g * Kext + kt + kc];
        *(short8*)&bLds[r * 40 + kc] = bv;
      }
      __syncthreads();
      short8 af[4];
      short8 bfr[4];
      #pragma unroll
      for (int m = 0; m < 4; m++)
        af[m] = *(const short8*)&aLds[(wm * 64 + m * 16 + (lane & 15)) * 40 + (lane >> 4) * 8];
      #pragma unroll
      for (int n = 0; n < 4; n++)
        bfr[n] = *(const short8*)&bLds[(wn * 64 + n * 16 + (lane & 15)) * 40 + (lane >> 4) * 8];
      #pragma unroll
      for (int m = 0; m < 4; m++)
        #pragma unroll
        for (int n = 0; n < 4; n++)
          acc[m][n] = __builtin_amdgcn_mfma_f32_16x16x32_bf16(af[m], bfr[n], acc[m][n], 0, 0, 0);
      __syncthreads();
    }
  }

  for (int m = 0; m < 4; m++){
    for (int n = 0; n < 4; n++){
      int gc = bn0 + wn * 64 + n * 16 + (lane & 15);
      float bv = bias[gc];
      for (int r = 0; r < 4; r++){
        int gr = bm0 + wm * 64 + m * 16 + (lane >> 4) * 4 + r;
        if (gr < N_NODES){
          float v2 = acc[m][n][r] + bv;
          if (v2 < 0.0f) v2 = 0.0f;
          C[(long long)gr * cout + gc] = v2;
        }
      }
    }
  }
}

extern "C" void kernel_launch(void* const* d_in, const int* in_sizes, int n_in,
                              void* d_out, int out_size, void* d_ws, size_t ws_size,
                              hipStream_t stream){
  const float* v = (const float*)d_in[0];
  const int* edges = (const int*)d_in[1];
  const int* row = edges;
  const int* col = edges + N_EDGES;

  const float* W00 = (const float*)d_in[2];
  const float* W01 = (const float*)d_in[3];
  const float* W02 = (const float*)d_in[4];
  const float* b0  = (const float*)d_in[5];
  const float* W10 = (const float*)d_in[6];
  const float* W11 = (const float*)d_in[7];
  const float* W12 = (const float*)d_in[8];
  const float* b1  = (const float*)d_in[9];
  const float* W20 = (const float*)d_in[10];
  const float* W21 = (const float*)d_in[11];
  const float* W22 = (const float*)d_in[12];
  const float* b2  = (const float*)d_in[13];

  // workspace layout (plain offsets, ~35 MB, same footprint as passing r5)
  int* ibase = (int*)d_ws;
  int* deg = ibase;                         // 20000
  int* cursor = ibase + 20000;              // 20000 (adjacent to deg for k_zero_i)
  int* offs = ibase + 40000;                // 20001
  float* dinv = (float*)(ibase + 60002);    // 20000
  int* ccol = ibase + 80002;                // 320000
  float* cw = (float*)(ibase + 400002);     // 320000
  short* Xb  = (short*)(ibase + 720002);                  // M_PAD*256 bf16
  short* Z1b = Xb + (long long)M_PAD * 256;
  short* Z2b = Z1b + (long long)M_PAD * 256;
  short* WT  = Z2b + (long long)M_PAD * 256;              // 512*768 bf16

  float* out = (float*)d_out;
  float* x1 = out;
  float* x2 = out + (long long)N_NODES * 128;
  float* x3 = out + (long long)N_NODES * (128 + 256);

  k_zero_i<<<(40000 + 255) / 256, 256, 0, stream>>>(deg, 40000);
  k_deg<<<(N_EDGES + 255) / 256, 256, 0, stream>>>(row, deg);
  k_scan<<<1, 256, 0, stream>>>(deg, offs, dinv);
  k_fill<<<(N_EDGES + 255) / 256, 256, 0, stream>>>(row, col, offs, cursor, dinv, ccol, cw);

  // grids: lanes = rows * (lda/4)
  int gXb128 = (int)(((long long)M_PAD * 32 + 255) / 256);
  int gXb256 = (int)(((long long)M_PAD * 64 + 255) / 256);
  int gNd128 = (int)(((long long)N_NODES * 32 + 255) / 256);
  int gNd256 = (int)(((long long)N_NODES * 64 + 255) / 256);

  // ---- layer 0: cin=86, Kext=96, lda=128, cout=128 ----
  k_xbv<<<gXb128, 256, 0, stream>>>(v, Xb, 86, 5, 128);
  k_lhat1v<<<gNd128, 256, 0, stream>>>(Xb, offs, ccol, cw, Z1b, 5, 128);
  k_lhat2v<<<gNd128, 256, 0, stream>>>(v, Z1b, offs, ccol, cw, Z2b, 86, 5, 128);
  k_wt<<<(128 * 288 + 255) / 256, 256, 0, stream>>>(W00, W01, W02, WT, 86, 128, 96);
  {
    dim3 g(M_PAD / 128, 128 / 128);
    k_gemm<<<g, 256, 0, stream>>>(Xb, Z1b, Z2b, WT, b0, x1, 128, 96, 128);
  }

  // ---- layer 1: cin=128, Kext=128, lda=128, cout=256 ----
  k_xbv<<<gXb128, 256, 0, stream>>>(x1, Xb, 128, 5, 128);
  k_lhat1v<<<gNd128, 256, 0, stream>>>(Xb, offs, ccol, cw, Z1b, 5, 128);
  k_lhat2v<<<gNd128, 256, 0, stream>>>(x1, Z1b, offs, ccol, cw, Z2b, 128, 5, 128);
  k_wt<<<(256 * 384 + 255) / 256, 256, 0, stream>>>(W10, W11, W12, WT, 128, 256, 128);
  {
    dim3 g(M_PAD / 128, 256 / 128);
    k_gemm<<<g, 256, 0, stream>>>(Xb, Z1b, Z2b, WT, b1, x2, 128, 128, 256);
  }

  // ---- layer 2: cin=256, Kext=256, lda=256, cout=512 ----
  k_xbv<<<gXb256, 256, 0, stream>>>(x2, Xb, 256, 6, 256);
  k_lhat1v<<<gNd256, 256, 0, stream>>>(Xb, offs, ccol, cw, Z1b, 6, 256);
  k_lhat2v<<<gNd256, 256, 0, stream>>>(x2, Z1b, offs, ccol, cw, Z2b, 256, 6, 256);
  k_wt<<<(512 * 768 + 255) / 256, 256, 0, stream>>>(W20, W21, W22, WT, 256, 512, 256);
  {
    dim3 g(M_PAD / 128, 512 / 128);
    k_gemm<<<g, 256, 0, stream>>>(Xb, Z1b, Z2b, WT, b2, x3, 256, 256, 512);
  }
}